// Round 1
// baseline (418.259 us; speedup 1.0000x reference)
//
#include <hip/hip_runtime.h>

// Apply a 2-qubit gate on qubits (5,12) of a 24-qubit state, batch=4 innermost.
// Element flat index: idx = b + 4*(q23 + 2*q22 + ... + 2^23*q0)
//   => qubit k stride = 2^(25-k) elements: q5 -> bit 20, q12 -> bit 13.
// Each thread owns one float4 (all 4 batch lanes) at each of the 4 (q5,q12)
// combos: 4 coalesced float4 loads, 4x4 matvec per batch lane, 4 float4 stores.

#define Q12_STRIDE 8192u      // 2^13 elements
#define Q5_STRIDE  1048576u   // 2^20 elements

__global__ __launch_bounds__(256) void quantum_gate_2q_kernel(
    const float* __restrict__ in,
    const float* __restrict__ gate,
    float* __restrict__ out)
{
    // 2^22 threads total; each covers 4 contiguous elements (the batch dim).
    unsigned t = blockIdx.x * blockDim.x + threadIdx.x;
    unsigned u = t << 2;  // compressed element index (support bits removed)
    // Insert zero bits at bit 13 (q12) and bit 20 (q5):
    // bits [0,12] stay; bits [13,18] shift up 1; bits [19,23] shift up 2.
    unsigned base = (u & 0x1FFFu) | ((u & 0x07E000u) << 1) | ((u & 0xF80000u) << 2);

    const float4* __restrict__ in4 = (const float4*)in;
    float4* __restrict__ out4 = (float4*)out;
    unsigned b = base >> 2;

    // s[j], j = q5*2 + q12 (gate in-axis order: axis2<->q5, axis3<->q12)
    float4 s0 = in4[b];                                      // q5=0,q12=0
    float4 s1 = in4[b + (Q12_STRIDE >> 2)];                  // q5=0,q12=1
    float4 s2 = in4[b + (Q5_STRIDE >> 2)];                   // q5=1,q12=0
    float4 s3 = in4[b + ((Q5_STRIDE + Q12_STRIDE) >> 2)];    // q5=1,q12=1

    // Gate loads are wave-uniform -> scalar loads, L1-resident.
    float g[16];
#pragma unroll
    for (int i = 0; i < 16; ++i) g[i] = gate[i];

    float4 r[4];
#pragma unroll
    for (int i = 0; i < 4; ++i) {
        r[i].x = g[i*4+0]*s0.x + g[i*4+1]*s1.x + g[i*4+2]*s2.x + g[i*4+3]*s3.x;
        r[i].y = g[i*4+0]*s0.y + g[i*4+1]*s1.y + g[i*4+2]*s2.y + g[i*4+3]*s3.y;
        r[i].z = g[i*4+0]*s0.z + g[i*4+1]*s1.z + g[i*4+2]*s2.z + g[i*4+3]*s3.z;
        r[i].w = g[i*4+0]*s0.w + g[i*4+1]*s1.w + g[i*4+2]*s2.w + g[i*4+3]*s3.w;
    }

    out4[b]                                   = r[0];
    out4[b + (Q12_STRIDE >> 2)]               = r[1];
    out4[b + (Q5_STRIDE >> 2)]                = r[2];
    out4[b + ((Q5_STRIDE + Q12_STRIDE) >> 2)] = r[3];
}

extern "C" void kernel_launch(void* const* d_in, const int* in_sizes, int n_in,
                              void* d_out, int out_size, void* d_ws, size_t ws_size,
                              hipStream_t stream) {
    const float* state = (const float*)d_in[0];
    const float* gate  = (const float*)d_in[1];
    float* out = (float*)d_out;

    // 2^24 * 4 elements total; 4 (q5,q12) combos x 4 batch lanes per thread
    // => 2^22 threads = 16384 blocks x 256.
    const int threads = 256;
    const int blocks = (1 << 22) / threads;
    quantum_gate_2q_kernel<<<blocks, threads, 0, stream>>>(state, gate, out);
}